// Round 4
// baseline (188.773 us; speedup 1.0000x reference)
//
#include <hip/hip_runtime.h>
#include <cfloat>
#include <cmath>

#define NP 10000
#define NG 1000
#define NC 80
#define LMAX 6

#define S_MULTI 12
#define S_BODY  16
#define RI_BIG  0x3fffffff
#define KMAX    0xFFFFFFFFFFFFFFFFull

// packkey(50.0f, 0): strong (inb) costs are < ~28, non-strong >= ~59 with this
// data's logit range (validated three rounds). If the gt's 5th-smallest
// candidate key >= TKEY we cannot prove the candidate set contains the true
// top-5 -> exact fallback.
#define TKEY    0xC248000000000000ull

// candidate list capacity per gt (expected ~410, worst-case big-gt ~950)
#define CAP     1024
// full-scan loop bounds over all NP preds
#define CMAIN   39
#define CTAIL   16          // 39*256 + 16 = 10000

// scatter kernel tiling: 1600 blocks, 25-iteration gt loops
#define GTILE   25
#define NGTILES 40          // 40*25 = 1000 gts
#define PBLKS   40          // 40*256 = 10240 >= NP

// candcnt padding: one counter per 128B line (kills atomic line contention)
#define CCSTRIDE 32

__device__ __forceinline__ bool lexless(float av, int ai, float bv, int bi) {
    return (av < bv) || (av == bv && ai < bi);
}

// float -> order-preserving u32 (no NaNs in this data), packed with index.
// ascending u64 order == lexicographic (value asc, index asc).
__device__ __forceinline__ unsigned long long packkey(float v, int idx) {
    unsigned u = __float_as_uint(v);
    u ^= (unsigned)(((int)u) >> 31) | 0x80000000u;
    return ((unsigned long long)u << 32) | (unsigned)idx;
}
__device__ __forceinline__ int keyidx(unsigned long long k) {
    return (int)(unsigned)(k & 0xFFFFFFFFu);
}

// Exact sequential +1e5 inflation (reference adds 1e5 once per loop iter).
__device__ __forceinline__ float inflate(float c, int k) {
    for (int q = 0; q < k; q++) c += 100000.0f;
    return c;
}

// Per-pair cost+iou from precomputed tables. Contraction OFF so every kernel
// that recomputes cost(i,j) agrees bit-exactly.
__device__ __forceinline__ void cost_iou(float4 p, float4 pn, float4 pi,
        float4 g, float4 cb, float4 Gn, float ga, float clsv,
        float& cc_out, float& iou_out) {
#pragma clang fp contract(off)
    float wx = fminf(p.z, g.z) - fmaxf(p.x, g.x); wx = fmaxf(wx, 0.0f);
    float wy = fminf(p.w, g.w) - fmaxf(p.y, g.y); wy = fmaxf(wy, 0.0f);
    float inter = wx * wy;
    float uni = pi.z + ga - inter;
    float iou = inter / fmaxf(uni, 1e-12f);
    float ex = fmaxf(p.z, g.z) - fminf(p.x, g.x); ex = fmaxf(ex, 0.0f);
    float ey = fmaxf(p.w, g.w) - fminf(p.y, g.y); ey = fmaxf(ey, 0.0f);
    float enc = ex * ey;
    float giou = iou - (enc - uni) / fmaxf(enc, 1e-12f);
    float l1 = ((fabsf(pn.x - Gn.x) + fabsf(pn.y - Gn.y))
                + fabsf(pn.z - Gn.z)) + fabsf(pn.w - Gn.w);
    float cc = clsv + l1 * 5.0f;
    cc = cc + (-giou * 2.0f);
    bool inb = (pi.x > g.x && pi.x < g.z && pi.y > g.y && pi.y < g.w);
    bool inc = (pi.x > cb.x && pi.x < cb.z && pi.y > cb.y && pi.y < cb.w);
    cc = cc + ((inb && inc) ? 0.0f : 100.0f);
    cc = cc + pi.w;
    cc_out = cc; iou_out = iou;
}

// Proven per-thread sorted top-5 insertion (static indices after unroll).
__device__ __forceinline__ void ins5k(unsigned long long* kv,
        unsigned long long key) {
    if (key < kv[4]) {
        kv[4] = key;
#pragma unroll
        for (int t = 4; t > 0; t--)
            if (kv[t] < kv[t-1]) { unsigned long long tv = kv[t]; kv[t] = kv[t-1]; kv[t-1] = tv; }
    }
}
__device__ __forceinline__ void ins5i(float* iv, float iou) {
    if (iou > iv[4]) {
        iv[4] = iou;
#pragma unroll
        for (int t = 4; t > 0; t--)
            if (iv[t] > iv[t-1]) { float tv = iv[t]; iv[t] = iv[t-1]; iv[t-1] = tv; }
    }
}

// ---------------------------------------------------------------------------
// Fused prep. Block ranges:
//  [0,40): init state; [40,197): cls table; [197,201): per-gt tables;
//  [201,2701): wave-per-pred validity + per-pred tables
// ---------------------------------------------------------------------------
#define CLS_TI 64
#define PB_CLS0 40
#define PB_G0   197
#define PB_V0   201
__global__ __launch_bounds__(256) void k_prep(const float* __restrict__ logits,
        const float* __restrict__ pb, const float* __restrict__ gb,
        const int* __restrict__ imgw, const int* __restrict__ imgh,
        float* __restrict__ clsval, float4* __restrict__ pnorm,
        float4* __restrict__ pinfo, float4* __restrict__ gcb,
        float4* __restrict__ gnm, float* __restrict__ gar,
        int* rowcnt, int* rowfirst, int* rowiter, int* prior, int* priorcol,
        int* colsum, int* scal, int* candcnt)
{
    __shared__ float sl[CLS_TI * (NC + 1)];
    int b = blockIdx.x;
    if (b < PB_CLS0) {
        int i = b * 256 + threadIdx.x;
        if (i < NP) {
            rowcnt[i] = 0; rowfirst[i] = 0x7fffffff; rowiter[i] = RI_BIG;
            prior[i] = 0; priorcol[i] = 0;
        }
        if (i < NG) { colsum[i] = 0; candcnt[i * CCSTRIDE] = 0; }
        if (i < 32) scal[i] = 0;
    } else if (b < PB_G0) {
        int i0 = (b - PB_CLS0) * CLS_TI;
        bool full = (i0 + CLS_TI) <= NP;
        if (full) {
            const float* src = logits + (size_t)i0 * NC;
            for (int e = threadIdx.x; e < CLS_TI * NC; e += 256) {
                int di = e / NC, c = e - di * NC;
                sl[di * (NC + 1) + c] = src[e];
            }
        } else {
            for (int e = threadIdx.x; e < CLS_TI * NC; e += 256) {
                int di = e / NC, c = e - di * NC;
                int i = i0 + di;
                sl[di * (NC + 1) + c] = (i < NP) ? logits[(size_t)i * NC + c] : 0.0f;
            }
        }
        __syncthreads();
        for (int e = threadIdx.x; e < CLS_TI * NC; e += 256) {
            int c = e >> 6, di = e & 63;
            int i = i0 + di;
            if (i >= NP) continue;
            float x = sl[di * (NC + 1) + c];
            float p = 1.0f / (1.0f + expf(-x));
            float neg = -log1pf(-(p - 1e-12f)) * 0.75f * (p * p);
            float om = 1.0f - p;
            float pos = -logf(p + 1e-12f) * 0.25f * (om * om);
            clsval[(size_t)c * NP + i] = (pos - neg) * 2.0f;   // * CLS_W
        }
    } else if (b < PB_V0) {
#pragma clang fp contract(off)
        int j = (b - PB_G0) * 256 + threadIdx.x;
        if (j < NG) {
            float fw = (float)imgw[0], fh = (float)imgh[0];
            float4 g = ((const float4*)gb)[j];
            float gcx = (g.x + g.z) * 0.5f, gcy = (g.y + g.w) * 0.5f;
            float gw = g.z - g.x, gh = g.w - g.y;
            float4 cb; cb.x = gcx - 2.5f * gw; cb.y = gcy - 2.5f * gh;
            cb.z = gcx + 2.5f * gw; cb.w = gcy + 2.5f * gh;
            gcb[j] = cb;
            float4 Gn; Gn.x = g.x / fw; Gn.y = g.y / fh; Gn.z = g.z / fw; Gn.w = g.w / fh;
            gnm[j] = Gn;
            gar[j] = (g.z - g.x) * (g.w - g.y);
        }
    } else {
#pragma clang fp contract(off)
        int wave = threadIdx.x >> 6;
        int lane = threadIdx.x & 63;
        int i = (b - PB_V0) * 4 + wave;
        if (i >= NP) return;
        float4 p = ((const float4*)pb)[i];
        float pcx = (p.x + p.z) * 0.5f, pcy = (p.y + p.w) * 0.5f;
        int vb = 0, vc = 0;
        const float4* gb4 = (const float4*)gb;
        // valid = any(inb) | any(inc): wave-level early exit as soon as
        // the disjunction is already established (~93% exit after 1 stride).
        for (int jb = 0; jb < NG; jb += 64) {
            int j = jb + lane;
            if (j < NG) {
                float4 g = gb4[j];
                vb |= (pcx > g.x && pcx < g.z && pcy > g.y && pcy < g.w) ? 1 : 0;
                float gcx = (g.x + g.z) * 0.5f, gcy = (g.y + g.w) * 0.5f;
                float gw = g.z - g.x, gh = g.w - g.y;
                vc |= (pcx > gcx - 2.5f * gw && pcx < gcx + 2.5f * gw &&
                       pcy > gcy - 2.5f * gh && pcy < gcy + 2.5f * gh) ? 1 : 0;
            }
            if (__any(vb | vc)) break;
        }
        int any = __any(vb | vc) ? 1 : 0;
        if (lane == 0) {
            float fw = (float)imgw[0], fh = (float)imgh[0];
            float4 pn; pn.x = p.x / fw; pn.y = p.y / fh; pn.z = p.z / fw; pn.w = p.w / fh;
            pnorm[i] = pn;
            float4 pi4; pi4.x = pcx; pi4.y = pcy;
            pi4.z = (p.z - p.x) * (p.w - p.y);
            pi4.w = any ? 0.0f : 10000.0f;
            pinfo[i] = pi4;
        }
    }
}

// ---------------------------------------------------------------------------
// k_scateval: overlap scan + IN-PLACE cost evaluation + scatter of finished
// (packkey, iou) pairs. Key insight (R3 post-mortem): at i = pblk*256+tid all
// per-pred inputs (pb4, pnorm, pinfo, clsval[glab*NP+i]) are COALESCED, and
// per-gt inputs live in LDS — so evaluating cost_iou here costs zero gathers,
// whereas deferring it to a gather phase cost 50us of scattered-load latency.
// Wave-aggregated slot reservation on 128B-padded counters (proven R3: no
// hot-line atomic serialization). Scatter writes are fire-and-forget stores.
// Order within a list is irrelevant (selection is order-independent).
// cnt may exceed CAP; extra writes dropped; k_cost2 falls back to the exact
// full scan for that gt. Same cost_iou + inputs as everywhere -> bit-exact.
// ---------------------------------------------------------------------------
__global__ __launch_bounds__(256) void k_scateval(const float* __restrict__ pb,
        const float* __restrict__ gb, const int* __restrict__ glab,
        const float* __restrict__ clsval,
        const float4* __restrict__ pnorm, const float4* __restrict__ pinfo,
        const float4* __restrict__ gcb, const float4* __restrict__ gnm,
        const float* __restrict__ gar,
        int* __restrict__ candcnt, unsigned long long* __restrict__ candkey,
        float* __restrict__ candiou)
{
    __shared__ float4 sg[GTILE];
    __shared__ float4 scb[GTILE];
    __shared__ float4 sGn[GTILE];
    __shared__ float  sga[GTILE];
    __shared__ int    slab[GTILE];
    int pblk = blockIdx.x / NGTILES;
    int gt0  = (blockIdx.x - pblk * NGTILES) * GTILE;
    int tid = threadIdx.x;
    int ln = tid & 63;
    if (tid < GTILE) {
        int j = gt0 + tid;
        sg[tid]  = ((const float4*)gb)[j];
        scb[tid] = gcb[j];
        sGn[tid] = gnm[j];
        sga[tid] = gar[j];
        slab[tid] = glab[j];
    }
    __syncthreads();
    int i = pblk * 256 + tid;
    bool live = (i < NP);
    int il = live ? i : 0;
    float4 p  = live ? ((const float4*)pb)[il]
                     : float4{-1e30f, -1e30f, -1e30f, -1e30f};
    float4 pn = pnorm[il];
    float4 pi = pinfo[il];
    for (int q = 0; q < GTILE; q++) {
        float4 gq = sg[q];
        bool o = live && (p.z > gq.x) & (gq.z > p.x) & (p.w > gq.y) & (gq.w > p.y);
        unsigned long long m = __ballot(o ? 1 : 0);
        if (m) {
            int j = gt0 + q;
            int basew = 0;
            if (ln == 0) basew = atomicAdd(&candcnt[j * CCSTRIDE], __popcll(m));
            basew = __shfl(basew, 0);
            if (o) {
                float cc, iou;
                cost_iou(p, pn, pi, gq, scb[q], sGn[q], sga[q],
                         clsval[(size_t)slab[q] * NP + i], cc, iou);
                int slot = basew + __popcll(m & ((1ull << ln) - 1ull));
                if (slot < CAP) {
                    candkey[(size_t)j * CAP + slot] = packkey(cc, i);
                    candiou[(size_t)j * CAP + slot] = iou;
                }
            }
        }
    }
}

// stride-7 LDS top-5 merge tree (proven). All threads must call (barriers).
__device__ __forceinline__ void tree57(unsigned long long* s_k, float* s_iv,
        int tid) {
    for (int w = 128; w > 0; w >>= 1) {
        if (tid < w) {
            int a = tid * 7, bb = (tid + w) * 7;
            unsigned long long ok[5]; float og[5];
            int pa = a, pbp = bb;
#pragma unroll
            for (int t = 0; t < 5; t++) {
                unsigned long long A = s_k[pa], B = s_k[pbp];
                if (A <= B) { ok[t] = A; pa++; } else { ok[t] = B; pbp++; }
            }
            int qa = a, qb = bb;
#pragma unroll
            for (int t = 0; t < 5; t++) {
                float A = s_iv[qa], B = s_iv[qb];
                if (A >= B) { og[t] = A; qa++; } else { og[t] = B; qb++; }
            }
#pragma unroll
            for (int t = 0; t < 5; t++) { s_k[a+t] = ok[t]; s_iv[a+t] = og[t]; }
        }
        __syncthreads();
    }
}

// ---------------------------------------------------------------------------
// k_cost2: one block per gt. Dense phase is now a CONTIGUOUS coalesced read
// of the gt's pre-evaluated (key, iou) list — zero gathers (R3's 50us was
// scattered-gather latency). Then the proven tree + gates + fused-merge
// epilogue. IoU pads are 0.0f == the exact iou of every non-candidate.
// Exactness gates:
//   (a) cnt > CAP (list overflow)  -> cold exact full scan
//   (b) s_k[4] >= TKEY (cannot prove >=5 strong candidates) -> cold scan
// Cold path = full 10000-pred per-thread top-5 (stride-1 coalesced) + same
// tree (proven code). Thread-0 epilogue folds the old k_costmerge: dk =
// trunc(sum of descending top-5 ious) (same summation order -> bit-exact),
// top5 store, row atomics.
// ---------------------------------------------------------------------------
__global__ __launch_bounds__(256) void k_cost2(
        const float* __restrict__ pb, const float* __restrict__ gb,
        const int* __restrict__ glab, const float* __restrict__ clsval,
        const float4* __restrict__ pnorm, const float4* __restrict__ pinfo,
        const float4* __restrict__ gcb, const float4* __restrict__ gnm,
        const float* __restrict__ gar,
        const int* __restrict__ candcnt,
        const unsigned long long* __restrict__ candkey,
        const float* __restrict__ candiou,
        int* __restrict__ rowcnt, int* __restrict__ rowfirst,
        int* __restrict__ rowiter, int* __restrict__ top5,
        int* __restrict__ dkarr)
{
    __shared__ unsigned long long s_k[256 * 7];
    __shared__ float s_iv[256 * 7];

    int j = blockIdx.x;
    int tid = threadIdx.x;

    int cnt = candcnt[j * CCSTRIDE];
    bool dense = (cnt <= CAP);        // block-uniform

    unsigned long long kv[5]; float iv[5];
#pragma unroll
    for (int t = 0; t < 5; t++) { kv[t] = KMAX; iv[t] = dense ? 0.0f : -1.0f; }

    if (dense) {
        const unsigned long long* ck = candkey + (size_t)j * CAP;
        const float* civ = candiou + (size_t)j * CAP;
        for (int q = tid; q < cnt; q += 256) {
            ins5k(kv, ck[q]);
            ins5i(iv, civ[q]);
        }
    } else {
        float4 g  = ((const float4*)gb)[j];
        float4 cb = gcb[j];
        float4 Gn = gnm[j];
        float  ga = gar[j];
        const float* clscol = clsval + (size_t)glab[j] * NP;
        const float4* pb4 = (const float4*)pb;
        for (int k = 0; k <= CMAIN; k++) {
            if (k == CMAIN && tid >= CTAIL) break;
            int i = tid + k * 256;
            float cc, iou;
            cost_iou(pb4[i], pnorm[i], pinfo[i], g, cb, Gn, ga, clscol[i], cc, iou);
            ins5k(kv, packkey(cc, i));
            ins5i(iv, iou);
        }
    }

    int base = tid * 7;
#pragma unroll
    for (int t = 0; t < 5; t++) { s_k[base+t] = kv[t]; s_iv[base+t] = iv[t]; }
    s_k[base+5] = KMAX; s_iv[base+5] = -2.0f;
    __syncthreads();
    tree57(s_k, s_iv, tid);

    // gate (b): block-uniform read of merged 5th key
    bool redo = dense && (s_k[4] >= TKEY);
    __syncthreads();            // everyone has read s_k[4] before any rewrite

    if (redo) {
        float4 g  = ((const float4*)gb)[j];
        float4 cb = gcb[j];
        float4 Gn = gnm[j];
        float  ga = gar[j];
        const float* clscol = clsval + (size_t)glab[j] * NP;
        const float4* pb4 = (const float4*)pb;
#pragma unroll
        for (int t = 0; t < 5; t++) { kv[t] = KMAX; iv[t] = -1.0f; }
        for (int k = 0; k <= CMAIN; k++) {
            if (k == CMAIN && tid >= CTAIL) break;
            int i = tid + k * 256;
            float cc, iou;
            cost_iou(pb4[i], pnorm[i], pinfo[i], g, cb, Gn, ga, clscol[i], cc, iou);
            ins5k(kv, packkey(cc, i));
            ins5i(iv, iou);
        }
#pragma unroll
        for (int t = 0; t < 5; t++) { s_k[base+t] = kv[t]; s_iv[base+t] = iv[t]; }
        s_k[base+5] = KMAX; s_iv[base+5] = -2.0f;
        __syncthreads();
        tree57(s_k, s_iv, tid);
    }

    if (tid == 0) {
        float s = (((s_iv[0] + s_iv[1]) + s_iv[2]) + s_iv[3]) + s_iv[4];
        int dk = (int)s;                 // astype(int32): truncation
        if (dk < 1) dk = 1;
        dkarr[j] = dk;
#pragma unroll
        for (int t = 0; t < 5; t++) top5[j * 5 + t] = keyidx(s_k[t]);
#pragma unroll
        for (int t = 0; t < 5; t++) {
            if (t < dk) {
                int r = keyidx(s_k[t]);
                atomicAdd(&rowcnt[r], 1);
                atomicMin(&rowfirst[r], j);
                atomicMin(&rowiter[r], -1);   // initially matched
            }
        }
    }
}

// ---------------------------------------------------------------------------
// Fused prior-detect + pfix + surv (R13-plain).
// Blocks [0,2500): rows 4b..4b+3; rows with rowcnt>1 -> prior=1 and
// cooperative argmin over 1000 gts -> priorcol, colsum++.
// Blocks [2500,2504): surviving single-pick rows -> colsum.
// ---------------------------------------------------------------------------
__global__ __launch_bounds__(256) void k_pfixsurv(const float* __restrict__ pb,
        const float* __restrict__ gb, const int* __restrict__ glab,
        const float* __restrict__ clsval,
        const float4* __restrict__ pnorm, const float4* __restrict__ pinfo,
        const float4* __restrict__ gcb, const float4* __restrict__ gnm,
        const float* __restrict__ gar,
        int* __restrict__ prior, int* __restrict__ priorcol,
        int* __restrict__ colsum,
        const int* __restrict__ rowcnt, const int* __restrict__ top5,
        const int* __restrict__ dkarr)
{
    int b = blockIdx.x;
    int tid = threadIdx.x;
    if (b >= 2500) {
        int j = (b - 2500) * 256 + tid;
        if (j >= NG) return;
        int c = 0;
        int dk = dkarr[j];
        for (int t = 0; t < dk; t++) if (rowcnt[top5[j * 5 + t]] == 1) c++;
        if (c) atomicAdd(&colsum[j], c);
        return;
    }
    __shared__ float rv[256]; __shared__ int ri[256];
    for (int q = 0; q < 4; q++) {
        int row = b * 4 + q;
        if (rowcnt[row] <= 1) continue;      // uniform across block
        if (tid == 0) prior[row] = 1;
        float4 p = ((const float4*)pb)[row];
        float4 pn = pnorm[row];
        float4 pi4 = pinfo[row];
        float best = FLT_MAX; int bj = 0x7fffffff;
        for (int j = tid; j < NG; j += 256) {
            float cc, iou;
            cost_iou(p, pn, pi4, ((const float4*)gb)[j], gcb[j], gnm[j], gar[j],
                     clsval[(size_t)glab[j] * NP + row], cc, iou);
            if (lexless(cc, j, best, bj)) { best = cc; bj = j; }
        }
        rv[tid] = best; ri[tid] = bj; __syncthreads();
        for (int w = 128; w > 0; w >>= 1) {
            if (tid < w) {
                float ov = rv[tid + w]; int oi = ri[tid + w];
                if (lexless(ov, oi, rv[tid], ri[tid])) { rv[tid] = ov; ri[tid] = oi; }
            }
            __syncthreads();
        }
        if (tid == 0) {
            priorcol[row] = ri[0];
            atomicAdd(&colsum[ri[0]], 1);
        }
        __syncthreads();
    }
}

// ---------------------------------------------------------------------------
// iterB: block per column; active iff colsum[j]==0.
// FAST PATH (proven R13): argmin over uninflated rows = first uninflated
// entry of the column's exact top-5 prefix; full-scan fallback if all 5
// inflated.
// ---------------------------------------------------------------------------
__global__ __launch_bounds__(256) void k_iterB(const float* __restrict__ pb,
        const float* __restrict__ gb, const int* __restrict__ glab,
        const float* __restrict__ clsval,
        const float4* __restrict__ pnorm, const float4* __restrict__ pinfo,
        const float4* __restrict__ gcb, const float4* __restrict__ gnm,
        const float* __restrict__ gar, const int* __restrict__ top5,
        int* __restrict__ rowiter, int* __restrict__ rowcnt,
        int* __restrict__ rowfirst, int* __restrict__ colsum,
        int* __restrict__ scal, int t)
{
    int j = blockIdx.x;
    if (colsum[j] != 0) return;
    int tid = threadIdx.x;
    if (tid == 0) scal[S_BODY + t] = 1;

    __shared__ int s_pos;
    if (tid == 0) {
        int pos = -1;
        for (int r = 0; r < 5; r++) {
            int i = top5[j * 5 + r];
            if (rowiter[i] >= t) { pos = i; break; }
        }
        s_pos = pos;
    }
    __syncthreads();
    int pos = s_pos;

    if (pos < 0) {
        // fallback: full argmin over uninflated rows
        float4 g  = ((const float4*)gb)[j];
        float4 cb = gcb[j];
        float4 Gn = gnm[j];
        float  ga = gar[j];
        const float* clscol = clsval + (size_t)glab[j] * NP;
        const float4* pb4 = (const float4*)pb;
        __shared__ float rv[256]; __shared__ int ri[256];
        float best = FLT_MAX; int bi = 0x7fffffff;
        for (int i = tid; i < NP; i += 256) {
            if (rowiter[i] < t) continue;
            float cc, iou;
            cost_iou(pb4[i], pnorm[i], pinfo[i], g, cb, Gn, ga, clscol[i], cc, iou);
            if (lexless(cc, i, best, bi)) { best = cc; bi = i; }
        }
        rv[tid] = best; ri[tid] = bi; __syncthreads();
        for (int w = 128; w > 0; w >>= 1) {
            if (tid < w) {
                float ov = rv[tid + w]; int oi = ri[tid + w];
                if (lexless(ov, oi, rv[tid], ri[tid])) { rv[tid] = ov; ri[tid] = oi; }
            }
            __syncthreads();
        }
        pos = ri[0];
    }

    if (tid == 0) {
        colsum[j] = 1;
        int old = atomicAdd(&rowcnt[pos], 1);
        if (old >= 1) scal[S_MULTI] = 1;
        atomicMin(&rowfirst[pos], j);
        atomicMin(&rowiter[pos], t);
    }
}

// ---------------------------------------------------------------------------
// iterC (m_fix, R13-plain): iff body ran at t && anymulti: prior rows
// (4 rows/block) re-argmin their inflated cost (exact sequential +1e5).
// ---------------------------------------------------------------------------
__global__ __launch_bounds__(256) void k_iterC(const float* __restrict__ pb,
        const float* __restrict__ gb, const int* __restrict__ glab,
        const float* __restrict__ clsval,
        const float4* __restrict__ pnorm, const float4* __restrict__ pinfo,
        const float4* __restrict__ gcb, const float4* __restrict__ gnm,
        const float* __restrict__ gar,
        const int* __restrict__ prior, const int* __restrict__ rowiter,
        int* __restrict__ priorcol, int* __restrict__ colsum,
        int* __restrict__ scal, int t)
{
    if (scal[S_BODY + t] == 0 || scal[S_MULTI] == 0) return;
    int b = blockIdx.x;
    int tid = threadIdx.x;
    __shared__ float rv[256]; __shared__ int ri[256];
    for (int q = 0; q < 4; q++) {
        int row = b * 4 + q;
        if (!prior[row]) continue;           // uniform across block
        int k = t - rowiter[row]; if (k < 0) k = 0;   // prior rows: -1 -> t+1
        float4 p = ((const float4*)pb)[row];
        float4 pn = pnorm[row];
        float4 pi4 = pinfo[row];
        float best = FLT_MAX; int bj = 0x7fffffff;
        for (int j = tid; j < NG; j += 256) {
            float cc, iou;
            cost_iou(p, pn, pi4, ((const float4*)gb)[j], gcb[j], gnm[j], gar[j],
                     clsval[(size_t)glab[j] * NP + row], cc, iou);
            float val = inflate(cc, k);
            if (lexless(val, j, best, bj)) { best = val; bj = j; }
        }
        rv[tid] = best; ri[tid] = bj; __syncthreads();
        for (int w = 128; w > 0; w >>= 1) {
            if (tid < w) {
                float ov = rv[tid + w]; int oi = ri[tid + w];
                if (lexless(ov, oi, rv[tid], ri[tid])) { rv[tid] = ov; ri[tid] = oi; }
            }
            __syncthreads();
        }
        if (tid == 0) {
            int nb = ri[0];
            int oldc = priorcol[row];
            if (nb != oldc) {
                atomicSub(&colsum[oldc], 1);
                atomicAdd(&colsum[nb], 1);
                priorcol[row] = nb;
            }
        }
        __syncthreads();
    }
}

// ---------------------------------------------------------------------------
// Final: fg = rowcnt>0; matched = priorcol (prior rows) else rowfirst. int32.
// ---------------------------------------------------------------------------
__global__ __launch_bounds__(256) void k_final(const int* __restrict__ rowcnt,
        const int* __restrict__ prior, const int* __restrict__ priorcol,
        const int* __restrict__ rowfirst, int* __restrict__ out)
{
    int i = blockIdx.x * 256 + threadIdx.x;
    if (i >= NP) return;
    int fg = rowcnt[i] > 0;
    out[i] = fg ? 1 : 0;
    out[NP + i] = fg ? (prior[i] ? priorcol[i] : rowfirst[i]) : 0;
}

extern "C" void kernel_launch(void* const* d_in, const int* in_sizes, int n_in,
                              void* d_out, int out_size, void* d_ws, size_t ws_size,
                              hipStream_t stream)
{
    (void)in_sizes; (void)n_in; (void)out_size; (void)ws_size;
    const float* logits = (const float*)d_in[0];
    const float* pboxes = (const float*)d_in[1];
    const float* gboxes = (const float*)d_in[2];
    const int*   glab   = (const int*)d_in[3];
    const int*   imgh   = (const int*)d_in[4];
    const int*   imgw   = (const int*)d_in[5];
    int* out = (int*)d_out;

    char* w = (char*)d_ws;
    float*  clsval  = (float*)(w);                    // 3,200,000
    float4* pnorm   = (float4*)(w + 3200000);         //   160,000
    float4* pinfo   = (float4*)(w + 3360000);         //   160,000
    float4* gcb     = (float4*)(w + 3520000);         //    16,000
    float4* gnm     = (float4*)(w + 3536000);         //    16,000
    float*  gar     = (float*)(w + 3552000);          //     4,000
    int* rowcnt     = (int*)(w + 3556000);            //    40,000
    int* rowfirst   = (int*)(w + 3596000);            //    40,000
    int* rowiter    = (int*)(w + 3636000);            //    40,000
    int* prior      = (int*)(w + 3676000);            //    40,000
    int* priorcol   = (int*)(w + 3716000);            //    40,000
    int* top5       = (int*)(w + 3756000);            //    20,000
    int* dkarr      = (int*)(w + 3776000);            //     4,000
    int* colsum     = (int*)(w + 3780000);            //     4,000
    int* scal       = (int*)(w + 3784000);            //       128
    int* candcnt    = (int*)(w + 3784128);            //   128,000 (padded 32x)
    unsigned long long* candkey = (unsigned long long*)(w + 3912128); // 8,192,000
    float* candiou  = (float*)(w + 12104128);         // 4,096,000

    hipLaunchKernelGGL(k_prep, dim3(2701), dim3(256), 0, stream,
                       logits, pboxes, gboxes, imgw, imgh,
                       clsval, pnorm, pinfo, gcb, gnm, gar,
                       rowcnt, rowfirst, rowiter, prior, priorcol, colsum, scal,
                       candcnt);
    hipLaunchKernelGGL(k_scateval, dim3(PBLKS * NGTILES), dim3(256), 0, stream,
                       pboxes, gboxes, glab, clsval, pnorm, pinfo, gcb, gnm, gar,
                       candcnt, candkey, candiou);
    hipLaunchKernelGGL(k_cost2, dim3(NG), dim3(256), 0, stream,
                       pboxes, gboxes, glab, clsval, pnorm, pinfo, gcb, gnm, gar,
                       candcnt, candkey, candiou,
                       rowcnt, rowfirst, rowiter, top5, dkarr);
    hipLaunchKernelGGL(k_pfixsurv, dim3(2504), dim3(256), 0, stream,
                       pboxes, gboxes, glab, clsval, pnorm, pinfo, gcb, gnm, gar,
                       prior, priorcol, colsum, rowcnt, top5, dkarr);
    for (int t = 0; t < LMAX; t++) {
        hipLaunchKernelGGL(k_iterB, dim3(NG), dim3(256), 0, stream,
                           pboxes, gboxes, glab, clsval, pnorm, pinfo, gcb, gnm, gar,
                           top5, rowiter, rowcnt, rowfirst, colsum, scal, t);
        hipLaunchKernelGGL(k_iterC, dim3(2500), dim3(256), 0, stream,
                           pboxes, gboxes, glab, clsval, pnorm, pinfo, gcb, gnm, gar,
                           prior, rowiter, priorcol, colsum, scal, t);
    }
    hipLaunchKernelGGL(k_final, dim3(40), dim3(256), 0, stream,
                       rowcnt, prior, priorcol, rowfirst, out);
}

// Round 6
// 159.621 us; speedup vs baseline: 1.1826x; 1.1826x over previous
//
#include <hip/hip_runtime.h>
#include <cfloat>
#include <cmath>

#define NP 10000
#define NG 1000
#define NC 80
#define LMAX 6

#define S_MULTI 12
#define S_BODY  16
#define RI_BIG  0x3fffffff
#define KMAX    0xFFFFFFFFFFFFFFFFull

// packkey(50.0f,0): strong (inb) costs < ~28, non-strong >= ~59 (validated
// across rounds incl. chunkless R2). If the gt's 5th-smallest key >= TKEY we
// cannot prove the candidate set covers the true top-5 -> exact full scan.
#define TKEY    0xC248000000000000ull

// chunkless full-scan loop bounds: 39*256 + 16 = 10000
#define CMAIN   39
#define CTAIL   16

// per-wave candidate region (LDS ints, aliased over s_iv): 4 waves x 384.
// Per-wave expected candidates ~100 (4% x 64 x 39), big-gt ~220, max ~280.
#define WCAP    384

__device__ __forceinline__ bool lexless(float av, int ai, float bv, int bi) {
    return (av < bv) || (av == bv && ai < bi);
}

// float -> order-preserving u32 (no NaNs in this data), packed with index.
// ascending u64 order == lexicographic (value asc, index asc).
__device__ __forceinline__ unsigned long long packkey(float v, int idx) {
    unsigned u = __float_as_uint(v);
    u ^= (unsigned)(((int)u) >> 31) | 0x80000000u;
    return ((unsigned long long)u << 32) | (unsigned)idx;
}
__device__ __forceinline__ int keyidx(unsigned long long k) {
    return (int)(unsigned)(k & 0xFFFFFFFFu);
}

// Exact sequential +1e5 inflation (reference adds 1e5 once per loop iter).
__device__ __forceinline__ float inflate(float c, int k) {
    for (int q = 0; q < k; q++) c += 100000.0f;
    return c;
}

// Per-pair cost+iou from precomputed tables. Contraction OFF so every kernel
// that recomputes cost(i,j) agrees bit-exactly.
__device__ __forceinline__ void cost_iou(float4 p, float4 pn, float4 pi,
        float4 g, float4 cb, float4 Gn, float ga, float clsv,
        float& cc_out, float& iou_out) {
#pragma clang fp contract(off)
    float wx = fminf(p.z, g.z) - fmaxf(p.x, g.x); wx = fmaxf(wx, 0.0f);
    float wy = fminf(p.w, g.w) - fmaxf(p.y, g.y); wy = fmaxf(wy, 0.0f);
    float inter = wx * wy;
    float uni = pi.z + ga - inter;
    float iou = inter / fmaxf(uni, 1e-12f);
    float ex = fmaxf(p.z, g.z) - fminf(p.x, g.x); ex = fmaxf(ex, 0.0f);
    float ey = fmaxf(p.w, g.w) - fminf(p.y, g.y); ey = fmaxf(ey, 0.0f);
    float enc = ex * ey;
    float giou = iou - (enc - uni) / fmaxf(enc, 1e-12f);
    float l1 = ((fabsf(pn.x - Gn.x) + fabsf(pn.y - Gn.y))
                + fabsf(pn.z - Gn.z)) + fabsf(pn.w - Gn.w);
    float cc = clsv + l1 * 5.0f;
    cc = cc + (-giou * 2.0f);
    bool inb = (pi.x > g.x && pi.x < g.z && pi.y > g.y && pi.y < g.w);
    bool inc = (pi.x > cb.x && pi.x < cb.z && pi.y > cb.y && pi.y < cb.w);
    cc = cc + ((inb && inc) ? 0.0f : 100.0f);
    cc = cc + pi.w;
    cc_out = cc; iou_out = iou;
}

// Proven per-thread sorted top-5 insertion (static indices after unroll).
// Per-thread top-5 is ALWAYS sufficient for the block top-5 (<=5 of the true
// top-5 can live on one thread) -> no sufficiency gate needed (R2-proven).
__device__ __forceinline__ void ins5k(unsigned long long* kv,
        unsigned long long key) {
    if (key < kv[4]) {
        kv[4] = key;
#pragma unroll
        for (int t = 4; t > 0; t--)
            if (kv[t] < kv[t-1]) { unsigned long long tv = kv[t]; kv[t] = kv[t-1]; kv[t-1] = tv; }
    }
}
__device__ __forceinline__ void ins5i(float* iv, float iou) {
    if (iou > iv[4]) {
        iv[4] = iou;
#pragma unroll
        for (int t = 4; t > 0; t--)
            if (iv[t] > iv[t-1]) { float tv = iv[t]; iv[t] = iv[t-1]; iv[t-1] = tv; }
    }
}

// ---------------------------------------------------------------------------
// Fused prep (verbatim R1). Block ranges:
//  [0,40): init state; [40,197): cls table; [197,201): per-gt tables;
//  [201,2701): wave-per-pred validity + per-pred tables
// ---------------------------------------------------------------------------
#define CLS_TI 64
#define PB_CLS0 40
#define PB_G0   197
#define PB_V0   201
__global__ __launch_bounds__(256) void k_prep(const float* __restrict__ logits,
        const float* __restrict__ pb, const float* __restrict__ gb,
        const int* __restrict__ imgw, const int* __restrict__ imgh,
        float* __restrict__ clsval, float4* __restrict__ pnorm,
        float4* __restrict__ pinfo, float4* __restrict__ gcb,
        float4* __restrict__ gnm, float* __restrict__ gar,
        int* rowcnt, int* rowfirst, int* rowiter, int* prior, int* priorcol,
        int* colsum, int* scal)
{
    __shared__ float sl[CLS_TI * (NC + 1)];
    int b = blockIdx.x;
    if (b < PB_CLS0) {
        int i = b * 256 + threadIdx.x;
        if (i < NP) {
            rowcnt[i] = 0; rowfirst[i] = 0x7fffffff; rowiter[i] = RI_BIG;
            prior[i] = 0; priorcol[i] = 0;
        }
        if (i < NG) colsum[i] = 0;
        if (i < 32) scal[i] = 0;
    } else if (b < PB_G0) {
        int i0 = (b - PB_CLS0) * CLS_TI;
        bool full = (i0 + CLS_TI) <= NP;
        if (full) {
            const float* src = logits + (size_t)i0 * NC;
            for (int e = threadIdx.x; e < CLS_TI * NC; e += 256) {
                int di = e / NC, c = e - di * NC;
                sl[di * (NC + 1) + c] = src[e];
            }
        } else {
            for (int e = threadIdx.x; e < CLS_TI * NC; e += 256) {
                int di = e / NC, c = e - di * NC;
                int i = i0 + di;
                sl[di * (NC + 1) + c] = (i < NP) ? logits[(size_t)i * NC + c] : 0.0f;
            }
        }
        __syncthreads();
        for (int e = threadIdx.x; e < CLS_TI * NC; e += 256) {
            int c = e >> 6, di = e & 63;
            int i = i0 + di;
            if (i >= NP) continue;
            float x = sl[di * (NC + 1) + c];
            float p = 1.0f / (1.0f + expf(-x));
            float neg = -log1pf(-(p - 1e-12f)) * 0.75f * (p * p);
            float om = 1.0f - p;
            float pos = -logf(p + 1e-12f) * 0.25f * (om * om);
            clsval[(size_t)c * NP + i] = (pos - neg) * 2.0f;   // * CLS_W
        }
    } else if (b < PB_V0) {
#pragma clang fp contract(off)
        int j = (b - PB_G0) * 256 + threadIdx.x;
        if (j < NG) {
            float fw = (float)imgw[0], fh = (float)imgh[0];
            float4 g = ((const float4*)gb)[j];
            float gcx = (g.x + g.z) * 0.5f, gcy = (g.y + g.w) * 0.5f;
            float gw = g.z - g.x, gh = g.w - g.y;
            float4 cb; cb.x = gcx - 2.5f * gw; cb.y = gcy - 2.5f * gh;
            cb.z = gcx + 2.5f * gw; cb.w = gcy + 2.5f * gh;
            gcb[j] = cb;
            float4 Gn; Gn.x = g.x / fw; Gn.y = g.y / fh; Gn.z = g.z / fw; Gn.w = g.w / fh;
            gnm[j] = Gn;
            gar[j] = (g.z - g.x) * (g.w - g.y);
        }
    } else {
#pragma clang fp contract(off)
        int wave = threadIdx.x >> 6;
        int lane = threadIdx.x & 63;
        int i = (b - PB_V0) * 4 + wave;
        if (i >= NP) return;
        float4 p = ((const float4*)pb)[i];
        float pcx = (p.x + p.z) * 0.5f, pcy = (p.y + p.w) * 0.5f;
        int vb = 0, vc = 0;
        const float4* gb4 = (const float4*)gb;
        // valid = any(inb) | any(inc): wave-level early exit as soon as
        // the disjunction is already established (~93% exit after 1 stride).
        for (int jb = 0; jb < NG; jb += 64) {
            int j = jb + lane;
            if (j < NG) {
                float4 g = gb4[j];
                vb |= (pcx > g.x && pcx < g.z && pcy > g.y && pcy < g.w) ? 1 : 0;
                float gcx = (g.x + g.z) * 0.5f, gcy = (g.y + g.w) * 0.5f;
                float gw = g.z - g.x, gh = g.w - g.y;
                vc |= (pcx > gcx - 2.5f * gw && pcx < gcx + 2.5f * gw &&
                       pcy > gcy - 2.5f * gh && pcy < gcy + 2.5f * gh) ? 1 : 0;
            }
            if (__any(vb | vc)) break;
        }
        int any = __any(vb | vc) ? 1 : 0;
        if (lane == 0) {
            float fw = (float)imgw[0], fh = (float)imgh[0];
            float4 pn; pn.x = p.x / fw; pn.y = p.y / fh; pn.z = p.z / fw; pn.w = p.w / fh;
            pnorm[i] = pn;
            float4 pi4; pi4.x = pcx; pi4.y = pcy;
            pi4.z = (p.z - p.x) * (p.w - p.y);
            pi4.w = any ? 0.0f : 10000.0f;
            pinfo[i] = pi4;
        }
    }
}

// stride-7 LDS top-5 merge tree (proven). All threads must call (barriers).
__device__ __forceinline__ void tree57(unsigned long long* s_k, float* s_iv,
        int tid) {
    for (int w = 128; w > 0; w >>= 1) {
        if (tid < w) {
            int a = tid * 7, bb = (tid + w) * 7;
            unsigned long long ok[5]; float og[5];
            int pa = a, pbp = bb;
#pragma unroll
            for (int t = 0; t < 5; t++) {
                unsigned long long A = s_k[pa], B = s_k[pbp];
                if (A <= B) { ok[t] = A; pa++; } else { ok[t] = B; pbp++; }
            }
            int qa = a, qb = bb;
#pragma unroll
            for (int t = 0; t < 5; t++) {
                float A = s_iv[qa], B = s_iv[qb];
                if (A >= B) { og[t] = A; qa++; } else { og[t] = B; qb++; }
            }
#pragma unroll
            for (int t = 0; t < 5; t++) { s_k[a+t] = ok[t]; s_iv[a+t] = og[t]; }
        }
        __syncthreads();
    }
}

// ---------------------------------------------------------------------------
// k_cost2: one block per gt (chunkless, R2-validated semantics) with R1's
// proven in-block compaction made ATOMIC-FREE:
//  Phase 1: cheap overlap scan (4 compares; overlap <=> iou > 0 exactly;
//    superset of the strong (inb) set). Each wave compacts hits into its
//    PRIVATE LDS region [wid*WCAP, wid*WCAP+WCAP) using a wave-uniform
//    register cursor (wbase += popcll(ballot)) — no LDS atomics, no shfl
//    (R1's 80 serialized LDS-atomic round-trips per block removed).
//    List order differs from R1 — irrelevant: keys embed the index, so the
//    top-5 selection is order-independent.
//  Phase 2: dense cost_iou over the 4 regions; per-thread 5-deep insertion
//    (unconditionally sufficient); proven stride-7 tree merge.
//  Gates (R2-proven control flow): any-wave-overflow -> primary full scan;
//    s_k[4] >= TKEY -> redo full scan. IoU pads on the dense path are 0.0f
//    == the exact iou of every non-candidate.
//  Thread-0 epilogue folds old k_costmerge (R2-proven): dk = trunc(sum of
//    descending top-5 ious), top5 store, row atomics. One launch removed,
//    merge-tree count halved vs R1 (1000 blocks vs 2000).
// ---------------------------------------------------------------------------
__global__ __launch_bounds__(256) void k_cost2(
        const float* __restrict__ pb, const float* __restrict__ gb,
        const int* __restrict__ glab, const float* __restrict__ clsval,
        const float4* __restrict__ pnorm, const float4* __restrict__ pinfo,
        const float4* __restrict__ gcb, const float4* __restrict__ gnm,
        const float* __restrict__ gar,
        int* __restrict__ rowcnt, int* __restrict__ rowfirst,
        int* __restrict__ rowiter, int* __restrict__ top5,
        int* __restrict__ dkarr)
{
    __shared__ unsigned long long s_k[256 * 7];
    __shared__ float s_iv[256 * 7];
    __shared__ int s_wcnt[4];
    int* s_list = (int*)s_iv;     // aliased; fully consumed before s_iv writes

    int j = blockIdx.x;
    int tid = threadIdx.x;
    int wid = tid >> 6;
    int ln  = tid & 63;
    float4 g  = ((const float4*)gb)[j];
    float4 cb = gcb[j];
    float4 Gn = gnm[j];
    float  ga = gar[j];
    const float* clscol = clsval + (size_t)glab[j] * NP;
    const float4* pb4 = (const float4*)pb;

    // ---- phase 1: cheap overlap scan, atomic-free per-wave compaction ----
    int wbase = 0;                       // wave-uniform cursor
    for (int k = 0; k <= CMAIN; k++) {
        if (k == CMAIN && tid >= CTAIL) break;
        int i = tid + k * 256;
        float4 p = pb4[i];
        bool o = (p.z > g.x) & (g.z > p.x) & (p.w > g.y) & (g.w > p.y);
        unsigned long long m = __ballot(o ? 1 : 0);
        if (o) {
            int slot = wbase + __popcll(m & ((1ull << ln) - 1ull));
            if (slot < WCAP) s_list[wid * WCAP + slot] = i;
        }
        wbase += __popcll(m);
    }
    if (ln == 0) s_wcnt[wid] = wbase;
    __syncthreads();
    int c0 = s_wcnt[0], c1 = s_wcnt[1], c2 = s_wcnt[2], c3 = s_wcnt[3];
    bool overflow = (c0 > WCAP) | (c1 > WCAP) | (c2 > WCAP) | (c3 > WCAP);

    unsigned long long kv[5]; float iv[5];
#pragma unroll
    for (int t = 0; t < 5; t++) { kv[t] = KMAX; iv[t] = overflow ? -1.0f : 0.0f; }

    if (!overflow) {
        // ---- phase 2: dense evals over the 4 wave regions ----
        for (int q = tid; q < c0; q += 256) {
            int i = s_list[q];
            float cc, iou;
            cost_iou(pb4[i], pnorm[i], pinfo[i], g, cb, Gn, ga, clscol[i], cc, iou);
            ins5k(kv, packkey(cc, i)); ins5i(iv, iou);
        }
        for (int q = tid; q < c1; q += 256) {
            int i = s_list[WCAP + q];
            float cc, iou;
            cost_iou(pb4[i], pnorm[i], pinfo[i], g, cb, Gn, ga, clscol[i], cc, iou);
            ins5k(kv, packkey(cc, i)); ins5i(iv, iou);
        }
        for (int q = tid; q < c2; q += 256) {
            int i = s_list[2 * WCAP + q];
            float cc, iou;
            cost_iou(pb4[i], pnorm[i], pinfo[i], g, cb, Gn, ga, clscol[i], cc, iou);
            ins5k(kv, packkey(cc, i)); ins5i(iv, iou);
        }
        for (int q = tid; q < c3; q += 256) {
            int i = s_list[3 * WCAP + q];
            float cc, iou;
            cost_iou(pb4[i], pnorm[i], pinfo[i], g, cb, Gn, ga, clscol[i], cc, iou);
            ins5k(kv, packkey(cc, i)); ins5i(iv, iou);
        }
    } else {
        // primary exact full scan (rare: a wave saw > WCAP hits)
        for (int k = 0; k <= CMAIN; k++) {
            if (k == CMAIN && tid >= CTAIL) break;
            int i = tid + k * 256;
            float cc, iou;
            cost_iou(pb4[i], pnorm[i], pinfo[i], g, cb, Gn, ga, clscol[i], cc, iou);
            ins5k(kv, packkey(cc, i)); ins5i(iv, iou);
        }
    }
    __syncthreads();              // list consumed; s_iv reusable

    int base = tid * 7;
#pragma unroll
    for (int t = 0; t < 5; t++) { s_k[base+t] = kv[t]; s_iv[base+t] = iv[t]; }
    s_k[base+5] = KMAX; s_iv[base+5] = -2.0f;
    __syncthreads();
    tree57(s_k, s_iv, tid);

    // gate: block-uniform read of merged 5th key (covers cnt<5 too: KMAX>=TKEY)
    bool redo = !overflow && (s_k[4] >= TKEY);
    __syncthreads();            // everyone has read s_k[4] before any rewrite

    if (redo) {
#pragma unroll
        for (int t = 0; t < 5; t++) { kv[t] = KMAX; iv[t] = -1.0f; }
        for (int k = 0; k <= CMAIN; k++) {
            if (k == CMAIN && tid >= CTAIL) break;
            int i = tid + k * 256;
            float cc, iou;
            cost_iou(pb4[i], pnorm[i], pinfo[i], g, cb, Gn, ga, clscol[i], cc, iou);
            ins5k(kv, packkey(cc, i)); ins5i(iv, iou);
        }
#pragma unroll
        for (int t = 0; t < 5; t++) { s_k[base+t] = kv[t]; s_iv[base+t] = iv[t]; }
        s_k[base+5] = KMAX; s_iv[base+5] = -2.0f;
        __syncthreads();
        tree57(s_k, s_iv, tid);
    }

    // folded costmerge epilogue (R2-proven; same summation order -> bit-exact)
    if (tid == 0) {
        float s = (((s_iv[0] + s_iv[1]) + s_iv[2]) + s_iv[3]) + s_iv[4];
        int dk = (int)s;                 // astype(int32): truncation
        if (dk < 1) dk = 1;
        dkarr[j] = dk;
#pragma unroll
        for (int t = 0; t < 5; t++) top5[j * 5 + t] = keyidx(s_k[t]);
#pragma unroll
        for (int t = 0; t < 5; t++) {
            if (t < dk) {
                int r = keyidx(s_k[t]);
                atomicAdd(&rowcnt[r], 1);
                atomicMin(&rowfirst[r], j);
                atomicMin(&rowiter[r], -1);   // initially matched
            }
        }
    }
}

// ---------------------------------------------------------------------------
// Fused prior-detect + pfix + surv (verbatim R1).
// Blocks [0,2500): rows 4b..4b+3; rows with rowcnt>1 -> prior=1 and
// cooperative argmin over 1000 gts -> priorcol, colsum++.
// Blocks [2500,2504): surviving single-pick rows -> colsum.
// ---------------------------------------------------------------------------
__global__ __launch_bounds__(256) void k_pfixsurv(const float* __restrict__ pb,
        const float* __restrict__ gb, const int* __restrict__ glab,
        const float* __restrict__ clsval,
        const float4* __restrict__ pnorm, const float4* __restrict__ pinfo,
        const float4* __restrict__ gcb, const float4* __restrict__ gnm,
        const float* __restrict__ gar,
        int* __restrict__ prior, int* __restrict__ priorcol,
        int* __restrict__ colsum,
        const int* __restrict__ rowcnt, const int* __restrict__ top5,
        const int* __restrict__ dkarr)
{
    int b = blockIdx.x;
    int tid = threadIdx.x;
    if (b >= 2500) {
        int j = (b - 2500) * 256 + tid;
        if (j >= NG) return;
        int c = 0;
        int dk = dkarr[j];
        for (int t = 0; t < dk; t++) if (rowcnt[top5[j * 5 + t]] == 1) c++;
        if (c) atomicAdd(&colsum[j], c);
        return;
    }
    __shared__ float rv[256]; __shared__ int ri[256];
    for (int q = 0; q < 4; q++) {
        int row = b * 4 + q;
        if (rowcnt[row] <= 1) continue;      // uniform across block
        if (tid == 0) prior[row] = 1;
        float4 p = ((const float4*)pb)[row];
        float4 pn = pnorm[row];
        float4 pi4 = pinfo[row];
        float best = FLT_MAX; int bj = 0x7fffffff;
        for (int j = tid; j < NG; j += 256) {
            float cc, iou;
            cost_iou(p, pn, pi4, ((const float4*)gb)[j], gcb[j], gnm[j], gar[j],
                     clsval[(size_t)glab[j] * NP + row], cc, iou);
            if (lexless(cc, j, best, bj)) { best = cc; bj = j; }
        }
        rv[tid] = best; ri[tid] = bj; __syncthreads();
        for (int w = 128; w > 0; w >>= 1) {
            if (tid < w) {
                float ov = rv[tid + w]; int oi = ri[tid + w];
                if (lexless(ov, oi, rv[tid], ri[tid])) { rv[tid] = ov; ri[tid] = oi; }
            }
            __syncthreads();
        }
        if (tid == 0) {
            priorcol[row] = ri[0];
            atomicAdd(&colsum[ri[0]], 1);
        }
        __syncthreads();
    }
}

// ---------------------------------------------------------------------------
// iterB (verbatim R1): block per column; active iff colsum[j]==0.
// FAST PATH: argmin over uninflated rows = first uninflated entry of the
// column's exact top-5 prefix; full-scan fallback if all 5 inflated.
// ---------------------------------------------------------------------------
__global__ __launch_bounds__(256) void k_iterB(const float* __restrict__ pb,
        const float* __restrict__ gb, const int* __restrict__ glab,
        const float* __restrict__ clsval,
        const float4* __restrict__ pnorm, const float4* __restrict__ pinfo,
        const float4* __restrict__ gcb, const float4* __restrict__ gnm,
        const float* __restrict__ gar, const int* __restrict__ top5,
        int* __restrict__ rowiter, int* __restrict__ rowcnt,
        int* __restrict__ rowfirst, int* __restrict__ colsum,
        int* __restrict__ scal, int t)
{
    int j = blockIdx.x;
    if (colsum[j] != 0) return;
    int tid = threadIdx.x;
    if (tid == 0) scal[S_BODY + t] = 1;

    __shared__ int s_pos;
    if (tid == 0) {
        int pos = -1;
        for (int r = 0; r < 5; r++) {
            int i = top5[j * 5 + r];
            if (rowiter[i] >= t) { pos = i; break; }
        }
        s_pos = pos;
    }
    __syncthreads();
    int pos = s_pos;

    if (pos < 0) {
        // fallback: full argmin over uninflated rows
        float4 g  = ((const float4*)gb)[j];
        float4 cb = gcb[j];
        float4 Gn = gnm[j];
        float  ga = gar[j];
        const float* clscol = clsval + (size_t)glab[j] * NP;
        const float4* pb4 = (const float4*)pb;
        __shared__ float rv[256]; __shared__ int ri[256];
        float best = FLT_MAX; int bi = 0x7fffffff;
        for (int i = tid; i < NP; i += 256) {
            if (rowiter[i] < t) continue;
            float cc, iou;
            cost_iou(pb4[i], pnorm[i], pinfo[i], g, cb, Gn, ga, clscol[i], cc, iou);
            if (lexless(cc, i, best, bi)) { best = cc; bi = i; }
        }
        rv[tid] = best; ri[tid] = bi; __syncthreads();
        for (int w = 128; w > 0; w >>= 1) {
            if (tid < w) {
                float ov = rv[tid + w]; int oi = ri[tid + w];
                if (lexless(ov, oi, rv[tid], ri[tid])) { rv[tid] = ov; ri[tid] = oi; }
            }
            __syncthreads();
        }
        pos = ri[0];
    }

    if (tid == 0) {
        colsum[j] = 1;
        int old = atomicAdd(&rowcnt[pos], 1);
        if (old >= 1) scal[S_MULTI] = 1;
        atomicMin(&rowfirst[pos], j);
        atomicMin(&rowiter[pos], t);
    }
}

// ---------------------------------------------------------------------------
// iterC (verbatim R1): iff body ran at t && anymulti: prior rows (4/block)
// re-argmin their inflated cost (exact sequential +1e5).
// ---------------------------------------------------------------------------
__global__ __launch_bounds__(256) void k_iterC(const float* __restrict__ pb,
        const float* __restrict__ gb, const int* __restrict__ glab,
        const float* __restrict__ clsval,
        const float4* __restrict__ pnorm, const float4* __restrict__ pinfo,
        const float4* __restrict__ gcb, const float4* __restrict__ gnm,
        const float* __restrict__ gar,
        const int* __restrict__ prior, const int* __restrict__ rowiter,
        int* __restrict__ priorcol, int* __restrict__ colsum,
        int* __restrict__ scal, int t)
{
    if (scal[S_BODY + t] == 0 || scal[S_MULTI] == 0) return;
    int b = blockIdx.x;
    int tid = threadIdx.x;
    __shared__ float rv[256]; __shared__ int ri[256];
    for (int q = 0; q < 4; q++) {
        int row = b * 4 + q;
        if (!prior[row]) continue;           // uniform across block
        int k = t - rowiter[row]; if (k < 0) k = 0;   // prior rows: -1 -> t+1
        float4 p = ((const float4*)pb)[row];
        float4 pn = pnorm[row];
        float4 pi4 = pinfo[row];
        float best = FLT_MAX; int bj = 0x7fffffff;
        for (int j = tid; j < NG; j += 256) {
            float cc, iou;
            cost_iou(p, pn, pi4, ((const float4*)gb)[j], gcb[j], gnm[j], gar[j],
                     clsval[(size_t)glab[j] * NP + row], cc, iou);
            float val = inflate(cc, k);
            if (lexless(val, j, best, bj)) { best = val; bj = j; }
        }
        rv[tid] = best; ri[tid] = bj; __syncthreads();
        for (int w = 128; w > 0; w >>= 1) {
            if (tid < w) {
                float ov = rv[tid + w]; int oi = ri[tid + w];
                if (lexless(ov, oi, rv[tid], ri[tid])) { rv[tid] = ov; ri[tid] = oi; }
            }
            __syncthreads();
        }
        if (tid == 0) {
            int nb = ri[0];
            int oldc = priorcol[row];
            if (nb != oldc) {
                atomicSub(&colsum[oldc], 1);
                atomicAdd(&colsum[nb], 1);
                priorcol[row] = nb;
            }
        }
        __syncthreads();
    }
}

// ---------------------------------------------------------------------------
// Final: fg = rowcnt>0; matched = priorcol (prior rows) else rowfirst. int32.
// ---------------------------------------------------------------------------
__global__ __launch_bounds__(256) void k_final(const int* __restrict__ rowcnt,
        const int* __restrict__ prior, const int* __restrict__ priorcol,
        const int* __restrict__ rowfirst, int* __restrict__ out)
{
    int i = blockIdx.x * 256 + threadIdx.x;
    if (i >= NP) return;
    int fg = rowcnt[i] > 0;
    out[i] = fg ? 1 : 0;
    out[NP + i] = fg ? (prior[i] ? priorcol[i] : rowfirst[i]) : 0;
}

extern "C" void kernel_launch(void* const* d_in, const int* in_sizes, int n_in,
                              void* d_out, int out_size, void* d_ws, size_t ws_size,
                              hipStream_t stream)
{
    (void)in_sizes; (void)n_in; (void)out_size; (void)ws_size;
    const float* logits = (const float*)d_in[0];
    const float* pboxes = (const float*)d_in[1];
    const float* gboxes = (const float*)d_in[2];
    const int*   glab   = (const int*)d_in[3];
    const int*   imgh   = (const int*)d_in[4];
    const int*   imgw   = (const int*)d_in[5];
    int* out = (int*)d_out;

    char* w = (char*)d_ws;
    float*  clsval  = (float*)(w);                    // 3,200,000
    float4* pnorm   = (float4*)(w + 3200000);         //   160,000
    float4* pinfo   = (float4*)(w + 3360000);         //   160,000
    float4* gcb     = (float4*)(w + 3520000);         //    16,000
    float4* gnm     = (float4*)(w + 3536000);         //    16,000
    float*  gar     = (float*)(w + 3552000);          //     4,000
    int* rowcnt     = (int*)(w + 3556000);            //    40,000
    int* rowfirst   = (int*)(w + 3596000);            //    40,000
    int* rowiter    = (int*)(w + 3636000);            //    40,000
    int* prior      = (int*)(w + 3676000);            //    40,000
    int* priorcol   = (int*)(w + 3716000);            //    40,000
    int* top5       = (int*)(w + 3756000);            //    20,000
    int* dkarr      = (int*)(w + 3776000);            //     4,000
    int* colsum     = (int*)(w + 3780000);            //     4,000
    int* scal       = (int*)(w + 3784000);            //       128

    hipLaunchKernelGGL(k_prep, dim3(2701), dim3(256), 0, stream,
                       logits, pboxes, gboxes, imgw, imgh,
                       clsval, pnorm, pinfo, gcb, gnm, gar,
                       rowcnt, rowfirst, rowiter, prior, priorcol, colsum, scal);
    hipLaunchKernelGGL(k_cost2, dim3(NG), dim3(256), 0, stream,
                       pboxes, gboxes, glab, clsval, pnorm, pinfo, gcb, gnm, gar,
                       rowcnt, rowfirst, rowiter, top5, dkarr);
    hipLaunchKernelGGL(k_pfixsurv, dim3(2504), dim3(256), 0, stream,
                       pboxes, gboxes, glab, clsval, pnorm, pinfo, gcb, gnm, gar,
                       prior, priorcol, colsum, rowcnt, top5, dkarr);
    for (int t = 0; t < LMAX; t++) {
        hipLaunchKernelGGL(k_iterB, dim3(NG), dim3(256), 0, stream,
                           pboxes, gboxes, glab, clsval, pnorm, pinfo, gcb, gnm, gar,
                           top5, rowiter, rowcnt, rowfirst, colsum, scal, t);
        hipLaunchKernelGGL(k_iterC, dim3(2500), dim3(256), 0, stream,
                           pboxes, gboxes, glab, clsval, pnorm, pinfo, gcb, gnm, gar,
                           prior, rowiter, priorcol, colsum, scal, t);
    }
    hipLaunchKernelGGL(k_final, dim3(40), dim3(256), 0, stream,
                       rowcnt, prior, priorcol, rowfirst, out);
}